// Round 9
// baseline (268.479 us; speedup 1.0000x reference)
//
#include <hip/hip_runtime.h>

// NNConv / MPNN layer, fully fused — v5: B-frags from L2 + 2 blocks/CU TLP.
//   h  = relu(ef @ W1 + b1)            [E,128]   (bf16 MFMA, K=16)
//   We = h @ W2 + b2                   [E,32,32] (bf16 MFMA, K=128, acc in regs, never stored)
//   msg= einsum('ei,eio->eo', nf[src], We)       (fp32 VALU on acc tiles)
//   out= segment_sum(msg, dst) + bias            (fp32 global atomics, out pre-init to bias)
//
// v5 (from round-8 counters: 100.5us, MfmaUtil 22, VALU 30, HBM 6.7, Occ 20 -> DS-pipe
// issue/latency bound at 8 waves/CU):
//  - W2s LDS staging DELETED. B-frags stream directly from W2p (L2-resident 256KB) as
//    16 global_load_dwordx4/wave/pass with 2-ks lookahead: 16 of 32 K-loop LDS b128
//    reads move to the idle VMEM pipe; no staging prologue/restage/drain.
//  - LDS 160K -> 62K/block; pbuf gets its OWN region (no alias) -> barrier A deleted
//    (C+D already order phase-3 reads vs next phase-0 writes); pbuf writes fold into
//    phase 3 (sv arrays gone). 3 barriers/pass.
//  - 512 blocks x 512 thr, __launch_bounds__(512,4) -> 2 blocks/CU, 16 waves/CU (2x TLP).
//  - atomics issued at ks==6 (newest VMEM: B-frag waits never force atomic completion).
//  - unchanged: deferred atomics, phase-0/1, phase-3 math, pbuf layout/XOR, setup kernel.

#define E_TOTAL   200000
#define N_NODES   50000
#define TILES     3125          // E_TOTAL / 64
#define OUT4      400000        // N_NODES*32 / 4
#define OUT4_BLKS 1563          // ceil(OUT4/256)
#define W2C_BLKS  64            // 16384 16B-chunks / 256
#define NBLK      512
#define NTL_BIG   53            // TILES % NBLK: blocks 0..52 own 7 tiles, rest 6
#define LDS_BYTES 61952         // 4K W1Ts + 16K Hs + 8.5K XsT + 32K pbuf (no alias)

typedef short short8  __attribute__((ext_vector_type(8)));
typedef float f32x4   __attribute__((ext_vector_type(4)));
typedef float f32x16  __attribute__((ext_vector_type(16)));

__device__ __forceinline__ short f2bf(float f) {
    // round-to-nearest-even fp32 -> bf16 (inputs finite)
    union { float f; unsigned u; } cv; cv.f = f;
    unsigned r = cv.u + 0x7fffu + ((cv.u >> 16) & 1u);
    return (short)(r >> 16);
}

// ---------------- setup: out = bias (float4); W2 f32 -> bf16 packed image (dest-major) ----
// W2p short idx = p*65536 + ks*8192 + ct*512 + lhg*256 + cc*8 + j
//   where c = ct*32+cc (= i*16 + o15), k = ks*16 + lhg*8 + j, src = W2[k*1024 + i*32 + p*16 + o15]
__global__ __launch_bounds__(256) void setup_kernel(const float* __restrict__ W2,
                                                    const float* __restrict__ bias,
                                                    float* __restrict__ out,
                                                    short* __restrict__ W2p) {
    int bid = blockIdx.x, tid = threadIdx.x;
    if (bid < OUT4_BLKS) {
        int i4 = bid * 256 + tid;
        if (i4 < OUT4) {
            float4 bv = *(const float4*)(bias + ((i4 & 7) << 2));
            *(float4*)(out + (size_t)i4 * 4) = bv;
        }
    } else {
        int q = (bid - OUT4_BLKS) * 256 + tid;    // 0..16383: one 16B dest chunk
        int p  = q >> 13;
        int ch = q & 8191;
        int ks = ch >> 10, ct = (ch >> 6) & 15, lhg = (ch >> 5) & 1, cc = ch & 31;
        int c  = ct * 32 + cc;
        int i  = c >> 4, o15 = c & 15;
        int ci = i * 32 + p * 16 + o15;
        int kb = ks * 16 + lhg * 8;
        short8 pk;
        #pragma unroll
        for (int j = 0; j < 8; ++j) pk[j] = f2bf(W2[(size_t)(kb + j) * 1024 + ci]);
        *(short8*)(W2p + (size_t)q * 8) = pk;
    }
}

// ---------------- main fused kernel ----------------
__global__ __launch_bounds__(512, 4) void mpnn_kernel(const float* __restrict__ nf,
                                                      const float* __restrict__ ef,
                                                      const int*   __restrict__ esrc,
                                                      const int*   __restrict__ edst,
                                                      const float* __restrict__ W1,
                                                      const float* __restrict__ b1,
                                                      const float* __restrict__ b2,
                                                      const short* __restrict__ W2p,
                                                      float* __restrict__ out) {
    extern __shared__ __align__(16) unsigned char smem[];
    short* W1Ts = (short*)(smem);              //   4096 B: [128 c][16 k] bf16 swizzled (prologue only)
    short* Hs   = (short*)(smem + 4096);       //  16384 B: [G 16][e^(G&7) 64] x 16B  (live D->C)
    float* XsT  = (float*)(smem + 20480);      //   8704 B: [32 i][68 e-pad] f32      (live phase0->C)
    float* pbuf = (float*)(smem + 29184);      //  32768 B: 8 slabs [64 e'][16 o] f32 (own region, no alias)

    const int tid = threadIdx.x;
    const int w   = tid >> 6;           // wave 0..7
    const int l31 = tid & 31;
    const int lh  = (tid >> 5) & 1;     // k-half within wave
    const int o15 = l31 & 15;
    const int ib  = l31 >> 4;           // i-lsb within packed col
    const int xbw = lh ^ ib;            // pbuf row-lsb XOR
    const int bid = blockIdx.x;
    const int ntl = (bid < NTL_BIG) ? 7 : 6;
    const int itn = 2 * ntl;
    const int bofs = (w << 10) + lh * 256 + l31 * 8;   // per-lane B-frag offset (t=0); +512 for t=1

    // ---------------- prologue: W1Ts; prefetch tile=bid ----------------
    float4 xreg; short8 efreg;
    float  b2v0, b2v1;
    {   // W1 [16][128] f32 -> W1Ts[c][k] bf16 swizzled (once per block)
        int g = tid * 4; int i = g >> 7; int c0 = g & 127;
        float4 v = *(const float4*)(W1 + g);
        float vv[4] = {v.x, v.y, v.z, v.w};
        #pragma unroll
        for (int u = 0; u < 4; ++u) {
            int c = c0 + u;
            W1Ts[c * 16 + (((i >> 3) ^ ((c >> 2) & 1)) << 3) + (i & 7)] = f2bf(vv[u]);
        }
    }
    {   // prefetch first tile: x gather (redundant esrc read per 8 threads) + ef frag
        int s = esrc[bid * 64 + (tid >> 3)];
        xreg = *(const float4*)(nf + (size_t)s * 32 + (tid & 7) * 4);
        int eL = l31 + ((w & 1) << 5);
        const float* ep = ef + (size_t)(bid * 64 + eL) * 16 + lh * 8;
        float4 a0 = *(const float4*)(ep);
        float4 a1 = *(const float4*)(ep + 4);
        efreg[0] = f2bf(a0.x); efreg[1] = f2bf(a0.y); efreg[2] = f2bf(a0.z); efreg[3] = f2bf(a0.w);
        efreg[4] = f2bf(a1.x); efreg[5] = f2bf(a1.y); efreg[6] = f2bf(a1.z); efreg[7] = f2bf(a1.w);
    }
    b2v0 = b2[(4 * w + ib) * 32 + o15];
    b2v1 = b2[(4 * w + 2 + ib) * 32 + o15];
    const int   cW1  = ((w >> 1) << 5) + l31;          // phase-1 hidden col
    const float b1v  = b1[cW1];

    __syncthreads();                                    // W1Ts visible
    const short8 w1frag = *(const short8*)(W1Ts + cW1 * 16 + ((lh ^ ((cW1 >> 2) & 1)) << 3));

    // deferred-atomic pending state (issued one iteration later, flushed after loop)
    float  pv0 = 0.f, pv1 = 0.f;
    int    po0 = 0,   po1 = 0;

    for (int it = 0; it < itn; ++it) {
        const int pass = (it >= ntl) ? 1 : 0;
        const int tile = bid + (it - pass * ntl) * NBLK;
        const int ebase = tile * 64;

        if (it == ntl) {   // switch to o-half 1: only the b2 constants change
            b2v0 = b2[(4 * w + ib) * 32 + 16 + o15];
            b2v1 = b2[(4 * w + 2 + ib) * 32 + 16 + o15];
        }

        // B-frag base for this pass + initial 2-ks prefetch (hides under phases 0/1)
        const short* Wb = W2p + (pass << 16) + bofs;
        short8 bf[16];
        bf[0] = *(const short8*)(Wb);           bf[1] = *(const short8*)(Wb + 512);
        bf[2] = *(const short8*)(Wb + 8192);    bf[3] = *(const short8*)(Wb + 8704);

        __syncthreads();   // D: prev iter's pbuf reads done -> Hs/XsT/pbuf writable

        // ---- phase 0: commit prefetched x -> XsT (transposed) ----
        {
            int e = tid >> 3, i4 = (tid & 7) * 4;
            XsT[(i4 + 0) * 68 + e] = xreg.x;
            XsT[(i4 + 1) * 68 + e] = xreg.y;
            XsT[(i4 + 2) * 68 + e] = xreg.z;
            XsT[(i4 + 3) * 68 + e] = xreg.w;
        }

        // ---- phase 1: h = relu(ef@W1+b1) -> Hs ----
        {
            f32x16 hacc;
            #pragma unroll
            for (int q = 0; q < 16; ++q) hacc[q] = 0.f;
            hacc = __builtin_amdgcn_mfma_f32_32x32x16_bf16(efreg, w1frag, hacc, 0, 0, 0);
            const int mh = w & 1, G1 = cW1 >> 3, j1 = cW1 & 7;
            #pragma unroll
            for (int r = 0; r < 16; ++r) {
                int ee = (r & 3) + ((r >> 2) << 3) + (lh << 2) + (mh << 5);
                float v = fmaxf(hacc[r] + b1v, 0.f);
                Hs[G1 * 512 + ((ee ^ (G1 & 7)) << 3) + j1] = f2bf(v);
            }
        }
        __syncthreads();   // E: Hs, XsT visible

        // next-tile index for prefetch (clamped on last iteration)
        int nit = it + 1; if (nit >= itn) nit = it;
        const int npass = (nit >= ntl) ? 1 : 0;
        const int nebase = (bid + (nit - npass * ntl) * NBLK) * 64;

        // ---- phase 2: K-loop; A-frags from LDS, B-frags from L2 (2-ks lookahead) ----
        f32x16 acc00, acc01, acc10, acc11;   // [t][mh]
        #pragma unroll
        for (int q = 0; q < 16; ++q) { acc00[q] = 0.f; acc01[q] = 0.f; acc10[q] = 0.f; acc11[q] = 0.f; }
        int pre_s = 0;
        #pragma unroll
        for (int ks = 0; ks < 8; ++ks) {
            const int G  = 2 * ks + lh;
            const int ax = ((l31 ^ (G & 7)) << 3);
            short8 afr0 = *(const short8*)(Hs + G * 512 + ax);          // e = l31
            short8 afr1 = *(const short8*)(Hs + G * 512 + ax + 256);    // e = l31+32
            if (ks < 6) {   // issue B-frags for ks+2 before this step's MFMAs
                bf[2 * ks + 4] = *(const short8*)(Wb + (ks + 2) * 8192);
                bf[2 * ks + 5] = *(const short8*)(Wb + (ks + 2) * 8192 + 512);
            }
            acc00 = __builtin_amdgcn_mfma_f32_32x32x16_bf16(afr0, bf[2 * ks    ], acc00, 0, 0, 0);
            acc01 = __builtin_amdgcn_mfma_f32_32x32x16_bf16(afr1, bf[2 * ks    ], acc01, 0, 0, 0);
            acc10 = __builtin_amdgcn_mfma_f32_32x32x16_bf16(afr0, bf[2 * ks + 1], acc10, 0, 0, 0);
            acc11 = __builtin_amdgcn_mfma_f32_32x32x16_bf16(afr1, bf[2 * ks + 1], acc11, 0, 0, 0);
            if (ks == 1) pre_s = esrc[nebase + (tid >> 3)];
            if (ks == 3) {
                int eL = l31 + ((w & 1) << 5);
                const float* ep = ef + (size_t)(nebase + eL) * 16 + lh * 8;
                float4 a0 = *(const float4*)(ep);
                float4 a1 = *(const float4*)(ep + 4);
                efreg[0] = f2bf(a0.x); efreg[1] = f2bf(a0.y); efreg[2] = f2bf(a0.z); efreg[3] = f2bf(a0.w);
                efreg[4] = f2bf(a1.x); efreg[5] = f2bf(a1.y); efreg[6] = f2bf(a1.z); efreg[7] = f2bf(a1.w);
            }
            if (ks == 5) xreg = *(const float4*)(nf + (size_t)pre_s * 32 + (tid & 7) * 4);
            if (ks == 6 && it > 0) {   // prev tile's atomics: newest VMEM, drain by barrier D
                atomicAdd(out + po0, pv0);
                atomicAdd(out + po1, pv1);
            }
        }

        // ---- phase 3: contract with x (broadcast b128); shfl ib-pair; store pbuf directly ----
        const int xc0 = 4 * w + ib, xc1 = 4 * w + 2 + ib;
        float* pslab = pbuf + (w << 10);
        #pragma unroll
        for (int rq = 0; rq < 4; ++rq) {
            const int eb = 8 * rq + 4 * lh;                 // e-base for r = rq*4+u
            f32x4 A0 = *(const f32x4*)(XsT + xc0 * 68 + eb);
            f32x4 B0 = *(const f32x4*)(XsT + xc1 * 68 + eb);
            f32x4 A1 = *(const f32x4*)(XsT + xc0 * 68 + eb + 32);
            f32x4 B1 = *(const f32x4*)(XsT + xc1 * 68 + eb + 32);
            #pragma unroll
            for (int u = 0; u < 4; ++u) {
                int r = rq * 4 + u;
                float v = A0[u] * (acc00[r] + b2v0) + B0[u] * (acc10[r] + b2v1);
                v += __shfl_xor(v, 16);
                float v1 = A1[u] * (acc01[r] + b2v0) + B1[u] * (acc11[r] + b2v1);
                v1 += __shfl_xor(v1, 16);
                int e = u + 8 * rq + 4 * lh + (ib << 5);
                pslab[((e ^ xbw) << 4) + o15] = ib ? v1 : v;   // own slab, 2-way banked
            }
        }
        __syncthreads();   // C: all pbuf slabs written
        {   // final reduce over 8 slabs -> pending registers (atomics issued next iteration)
            int idx = tid;
            int e = idx >> 4, oo = idx & 15;
            int xbE = ((e >> 2) ^ (e >> 5)) & 1;
            int a = ((e ^ xbE) << 4) + oo;
            pv0 = ((pbuf[a]          + pbuf[a + 1024]) + (pbuf[a + 2048] + pbuf[a + 3072]))
                + ((pbuf[a + 4096]   + pbuf[a + 5120]) + (pbuf[a + 6144] + pbuf[a + 7168]));
            po0 = edst[ebase + e] * 32 + (pass << 4) + oo;
            idx = tid + 512;
            e = idx >> 4; oo = idx & 15;
            xbE = ((e >> 2) ^ (e >> 5)) & 1;
            a = ((e ^ xbE) << 4) + oo;
            pv1 = ((pbuf[a]          + pbuf[a + 1024]) + (pbuf[a + 2048] + pbuf[a + 3072]))
                + ((pbuf[a + 4096]   + pbuf[a + 5120]) + (pbuf[a + 6144] + pbuf[a + 7168]));
            po1 = edst[ebase + e] * 32 + (pass << 4) + oo;
        }
    }
    // flush last tile's atomics
    atomicAdd(out + po0, pv0);
    atomicAdd(out + po1, pv1);
}

extern "C" void kernel_launch(void* const* d_in, const int* in_sizes, int n_in,
                              void* d_out, int out_size, void* d_ws, size_t ws_size,
                              hipStream_t stream) {
    const float* nf   = (const float*)d_in[0];
    const float* ef   = (const float*)d_in[1];
    const int*   src  = (const int*)  d_in[2];
    const int*   dst  = (const int*)  d_in[3];
    const float* W1   = (const float*)d_in[4];
    const float* b1   = (const float*)d_in[5];
    const float* W2   = (const float*)d_in[6];
    const float* b2   = (const float*)d_in[7];
    const float* bias = (const float*)d_in[8];
    float* out = (float*)d_out;
    short* W2p = (short*)d_ws;                 // 262144 B bf16 W2, packed per o-half (L2-resident)

    setup_kernel<<<OUT4_BLKS + W2C_BLKS, 256, 0, stream>>>(W2, bias, out, W2p);
    mpnn_kernel<<<NBLK, 512, LDS_BYTES, stream>>>(nf, ef, src, dst, W1, b1, b2, W2p, out);
}

// Round 11
// 208.793 us; speedup vs baseline: 1.2859x; 1.2859x over previous
//
#include <hip/hip_runtime.h>

// NNConv / MPNN layer, fully fused — v6: v5 structure + spill-proof register plan.
//   h  = relu(ef @ W1 + b1)            [E,128]   (bf16 MFMA, K=16)
//   We = h @ W2 + b2                   [E,32,32] (bf16 MFMA, K=128, acc in regs, never stored)
//   msg= einsum('ei,eio->eo', nf[src], We)       (fp32 VALU on acc tiles)
//   out= segment_sum(msg, dst) + bias            (fp32 global atomics, out pre-init to bias)
//
// v5 post-mortem: __launch_bounds__(512,4) + bf[16] (64 VGPR) => compiler clamped to 64
// VGPR, spilled acc+bf to scratch (FETCH 28->193MB, WRITE 25->60MB), 2x slower. All v5
// indexing PASSED, so v6 keeps the structure and fixes only the register plan:
//  - rolling 6-reg B-frag window (bA/bB/bC pairs, 24 VGPR, static names, 2-ks lookahead)
//    instead of bf[16] (64 VGPR).
//  - __launch_bounds__(512,2) (proven: v4 compiled to 116 VGPR under it). Est live set
//    ~110 <= 128 -> no spill; with 62KB LDS the HW runs 2 blocks/CU when VGPR <= 128.
//  - unchanged from v5: no W2s staging (B-frags stream from L2-resident W2p), 3
//    barriers/pass, pbuf own region + fold into phase 3, atomics at ks==6, setup kernel.

#define E_TOTAL   200000
#define N_NODES   50000
#define TILES     3125          // E_TOTAL / 64
#define OUT4      400000        // N_NODES*32 / 4
#define OUT4_BLKS 1563          // ceil(OUT4/256)
#define W2C_BLKS  64            // 16384 16B-chunks / 256
#define NBLK      512
#define NTL_BIG   53            // TILES % NBLK: blocks 0..52 own 7 tiles, rest 6
#define LDS_BYTES 61952         // 4K W1Ts + 16K Hs + 8.5K XsT + 32K pbuf (no alias)

typedef short short8  __attribute__((ext_vector_type(8)));
typedef float f32x4   __attribute__((ext_vector_type(4)));
typedef float f32x16  __attribute__((ext_vector_type(16)));

__device__ __forceinline__ short f2bf(float f) {
    // round-to-nearest-even fp32 -> bf16 (inputs finite)
    union { float f; unsigned u; } cv; cv.f = f;
    unsigned r = cv.u + 0x7fffu + ((cv.u >> 16) & 1u);
    return (short)(r >> 16);
}

// ---------------- setup: out = bias (float4); W2 f32 -> bf16 packed image (dest-major) ----
// W2p short idx = p*65536 + ks*8192 + ct*512 + lhg*256 + cc*8 + j
//   where c = ct*32+cc (= i*16 + o15), k = ks*16 + lhg*8 + j, src = W2[k*1024 + i*32 + p*16 + o15]
__global__ __launch_bounds__(256) void setup_kernel(const float* __restrict__ W2,
                                                    const float* __restrict__ bias,
                                                    float* __restrict__ out,
                                                    short* __restrict__ W2p) {
    int bid = blockIdx.x, tid = threadIdx.x;
    if (bid < OUT4_BLKS) {
        int i4 = bid * 256 + tid;
        if (i4 < OUT4) {
            float4 bv = *(const float4*)(bias + ((i4 & 7) << 2));
            *(float4*)(out + (size_t)i4 * 4) = bv;
        }
    } else {
        int q = (bid - OUT4_BLKS) * 256 + tid;    // 0..16383: one 16B dest chunk
        int p  = q >> 13;
        int ch = q & 8191;
        int ks = ch >> 10, ct = (ch >> 6) & 15, lhg = (ch >> 5) & 1, cc = ch & 31;
        int c  = ct * 32 + cc;
        int i  = c >> 4, o15 = c & 15;
        int ci = i * 32 + p * 16 + o15;
        int kb = ks * 16 + lhg * 8;
        short8 pk;
        #pragma unroll
        for (int j = 0; j < 8; ++j) pk[j] = f2bf(W2[(size_t)(kb + j) * 1024 + ci]);
        *(short8*)(W2p + (size_t)q * 8) = pk;
    }
}

// ---------------- main fused kernel ----------------
__global__ __launch_bounds__(512, 2) void mpnn_kernel(const float* __restrict__ nf,
                                                      const float* __restrict__ ef,
                                                      const int*   __restrict__ esrc,
                                                      const int*   __restrict__ edst,
                                                      const float* __restrict__ W1,
                                                      const float* __restrict__ b1,
                                                      const float* __restrict__ b2,
                                                      const short* __restrict__ W2p,
                                                      float* __restrict__ out) {
    extern __shared__ __align__(16) unsigned char smem[];
    short* W1Ts = (short*)(smem);              //   4096 B: [128 c][16 k] bf16 swizzled (prologue only)
    short* Hs   = (short*)(smem + 4096);       //  16384 B: [G 16][e^(G&7) 64] x 16B  (live D->C)
    float* XsT  = (float*)(smem + 20480);      //   8704 B: [32 i][68 e-pad] f32      (live phase0->C)
    float* pbuf = (float*)(smem + 29184);      //  32768 B: 8 slabs [64 e'][16 o] f32 (own region, no alias)

    const int tid = threadIdx.x;
    const int w   = tid >> 6;           // wave 0..7
    const int l31 = tid & 31;
    const int lh  = (tid >> 5) & 1;     // k-half within wave
    const int o15 = l31 & 15;
    const int ib  = l31 >> 4;           // i-lsb within packed col
    const int xbw = lh ^ ib;            // pbuf row-lsb XOR
    const int bid = blockIdx.x;
    const int ntl = (bid < NTL_BIG) ? 7 : 6;
    const int itn = 2 * ntl;
    const int bofs = (w << 10) + lh * 256 + l31 * 8;   // per-lane B-frag offset (t=0); +512 for t=1

    // ---------------- prologue: W1Ts; prefetch tile=bid ----------------
    float4 xreg; short8 efreg;
    float  b2v0, b2v1;
    {   // W1 [16][128] f32 -> W1Ts[c][k] bf16 swizzled (once per block)
        int g = tid * 4; int i = g >> 7; int c0 = g & 127;
        float4 v = *(const float4*)(W1 + g);
        float vv[4] = {v.x, v.y, v.z, v.w};
        #pragma unroll
        for (int u = 0; u < 4; ++u) {
            int c = c0 + u;
            W1Ts[c * 16 + (((i >> 3) ^ ((c >> 2) & 1)) << 3) + (i & 7)] = f2bf(vv[u]);
        }
    }
    {   // prefetch first tile: x gather (redundant esrc read per 8 threads) + ef frag
        int s = esrc[bid * 64 + (tid >> 3)];
        xreg = *(const float4*)(nf + (size_t)s * 32 + (tid & 7) * 4);
        int eL = l31 + ((w & 1) << 5);
        const float* ep = ef + (size_t)(bid * 64 + eL) * 16 + lh * 8;
        float4 a0 = *(const float4*)(ep);
        float4 a1 = *(const float4*)(ep + 4);
        efreg[0] = f2bf(a0.x); efreg[1] = f2bf(a0.y); efreg[2] = f2bf(a0.z); efreg[3] = f2bf(a0.w);
        efreg[4] = f2bf(a1.x); efreg[5] = f2bf(a1.y); efreg[6] = f2bf(a1.z); efreg[7] = f2bf(a1.w);
    }
    b2v0 = b2[(4 * w + ib) * 32 + o15];
    b2v1 = b2[(4 * w + 2 + ib) * 32 + o15];
    const int   cW1  = ((w >> 1) << 5) + l31;          // phase-1 hidden col
    const float b1v  = b1[cW1];

    __syncthreads();                                    // W1Ts visible
    const short8 w1frag = *(const short8*)(W1Ts + cW1 * 16 + ((lh ^ ((cW1 >> 2) & 1)) << 3));

    // deferred-atomic pending state (issued one iteration later, flushed after loop)
    float  pv0 = 0.f, pv1 = 0.f;
    int    po0 = 0,   po1 = 0;

    for (int it = 0; it < itn; ++it) {
        const int pass = (it >= ntl) ? 1 : 0;
        const int tile = bid + (it - pass * ntl) * NBLK;
        const int ebase = tile * 64;

        if (it == ntl) {   // switch to o-half 1: only the b2 constants change
            b2v0 = b2[(4 * w + ib) * 32 + 16 + o15];
            b2v1 = b2[(4 * w + 2 + ib) * 32 + 16 + o15];
        }

        // B-frag base for this pass; prefetch ks0/ks1 into the rolling window (hides
        // under phases 0/1). bA = current ks, bB = ks+1, bC = ks+2 in flight.
        const short* Wb = W2p + (pass << 16) + bofs;
        short8 bA0 = *(const short8*)(Wb);
        short8 bA1 = *(const short8*)(Wb + 512);
        short8 bB0 = *(const short8*)(Wb + 8192);
        short8 bB1 = *(const short8*)(Wb + 8704);

        __syncthreads();   // D: prev iter's pbuf reads done -> Hs/XsT/pbuf writable

        // ---- phase 0: commit prefetched x -> XsT (transposed) ----
        {
            int e = tid >> 3, i4 = (tid & 7) * 4;
            XsT[(i4 + 0) * 68 + e] = xreg.x;
            XsT[(i4 + 1) * 68 + e] = xreg.y;
            XsT[(i4 + 2) * 68 + e] = xreg.z;
            XsT[(i4 + 3) * 68 + e] = xreg.w;
        }

        // ---- phase 1: h = relu(ef@W1+b1) -> Hs ----
        {
            f32x16 hacc;
            #pragma unroll
            for (int q = 0; q < 16; ++q) hacc[q] = 0.f;
            hacc = __builtin_amdgcn_mfma_f32_32x32x16_bf16(efreg, w1frag, hacc, 0, 0, 0);
            const int mh = w & 1, G1 = cW1 >> 3, j1 = cW1 & 7;
            #pragma unroll
            for (int r = 0; r < 16; ++r) {
                int ee = (r & 3) + ((r >> 2) << 3) + (lh << 2) + (mh << 5);
                float v = fmaxf(hacc[r] + b1v, 0.f);
                Hs[G1 * 512 + ((ee ^ (G1 & 7)) << 3) + j1] = f2bf(v);
            }
        }
        __syncthreads();   // E: Hs, XsT visible

        // next-tile index for prefetch (clamped on last iteration)
        int nit = it + 1; if (nit >= itn) nit = it;
        const int npass = (nit >= ntl) ? 1 : 0;
        const int nebase = (bid + (nit - npass * ntl) * NBLK) * 64;

        // ---- phase 2: K-loop; A-frags from LDS, B-frags from L2 via rolling window ----
        f32x16 acc00, acc01, acc10, acc11;   // [t][mh]
        #pragma unroll
        for (int q = 0; q < 16; ++q) { acc00[q] = 0.f; acc01[q] = 0.f; acc10[q] = 0.f; acc11[q] = 0.f; }
        int pre_s = 0;
        #pragma unroll
        for (int ks = 0; ks < 8; ++ks) {
            const int G  = 2 * ks + lh;
            const int ax = ((l31 ^ (G & 7)) << 3);
            short8 afr0 = *(const short8*)(Hs + G * 512 + ax);          // e = l31
            short8 afr1 = *(const short8*)(Hs + G * 512 + ax + 256);    // e = l31+32
            short8 bC0, bC1;
            if (ks < 6) {   // issue ks+2's B-frags before this step's MFMAs
                bC0 = *(const short8*)(Wb + (ks + 2) * 8192);
                bC1 = *(const short8*)(Wb + (ks + 2) * 8192 + 512);
            }
            acc00 = __builtin_amdgcn_mfma_f32_32x32x16_bf16(afr0, bA0, acc00, 0, 0, 0);
            acc01 = __builtin_amdgcn_mfma_f32_32x32x16_bf16(afr1, bA0, acc01, 0, 0, 0);
            acc10 = __builtin_amdgcn_mfma_f32_32x32x16_bf16(afr0, bA1, acc10, 0, 0, 0);
            acc11 = __builtin_amdgcn_mfma_f32_32x32x16_bf16(afr1, bA1, acc11, 0, 0, 0);
            if (ks == 1) pre_s = esrc[nebase + (tid >> 3)];
            if (ks == 3) {
                int eL = l31 + ((w & 1) << 5);
                const float* ep = ef + (size_t)(nebase + eL) * 16 + lh * 8;
                float4 a0 = *(const float4*)(ep);
                float4 a1 = *(const float4*)(ep + 4);
                efreg[0] = f2bf(a0.x); efreg[1] = f2bf(a0.y); efreg[2] = f2bf(a0.z); efreg[3] = f2bf(a0.w);
                efreg[4] = f2bf(a1.x); efreg[5] = f2bf(a1.y); efreg[6] = f2bf(a1.z); efreg[7] = f2bf(a1.w);
            }
            if (ks == 5) xreg = *(const float4*)(nf + (size_t)pre_s * 32 + (tid & 7) * 4);
            if (ks == 6 && it > 0) {   // prev tile's atomics: newest VMEM, drain by barrier D
                atomicAdd(out + po0, pv0);
                atomicAdd(out + po1, pv1);
            }
            // roll the window (static names, no arrays -> no scratch)
            bA0 = bB0; bA1 = bB1;
            if (ks < 6) { bB0 = bC0; bB1 = bC1; }
        }

        // ---- phase 3: contract with x (broadcast b128); shfl ib-pair; store pbuf directly ----
        const int xc0 = 4 * w + ib, xc1 = 4 * w + 2 + ib;
        float* pslab = pbuf + (w << 10);
        #pragma unroll
        for (int rq = 0; rq < 4; ++rq) {
            const int eb = 8 * rq + 4 * lh;                 // e-base for r = rq*4+u
            f32x4 A0 = *(const f32x4*)(XsT + xc0 * 68 + eb);
            f32x4 B0 = *(const f32x4*)(XsT + xc1 * 68 + eb);
            f32x4 A1 = *(const f32x4*)(XsT + xc0 * 68 + eb + 32);
            f32x4 B1 = *(const f32x4*)(XsT + xc1 * 68 + eb + 32);
            #pragma unroll
            for (int u = 0; u < 4; ++u) {
                int r = rq * 4 + u;
                float v = A0[u] * (acc00[r] + b2v0) + B0[u] * (acc10[r] + b2v1);
                v += __shfl_xor(v, 16);
                float v1 = A1[u] * (acc01[r] + b2v0) + B1[u] * (acc11[r] + b2v1);
                v1 += __shfl_xor(v1, 16);
                int e = u + 8 * rq + 4 * lh + (ib << 5);
                pslab[((e ^ xbw) << 4) + o15] = ib ? v1 : v;   // own slab, 2-way banked
            }
        }
        __syncthreads();   // C: all pbuf slabs written
        {   // final reduce over 8 slabs -> pending registers (atomics issued next iteration)
            int idx = tid;
            int e = idx >> 4, oo = idx & 15;
            int xbE = ((e >> 2) ^ (e >> 5)) & 1;
            int a = ((e ^ xbE) << 4) + oo;
            pv0 = ((pbuf[a]          + pbuf[a + 1024]) + (pbuf[a + 2048] + pbuf[a + 3072]))
                + ((pbuf[a + 4096]   + pbuf[a + 5120]) + (pbuf[a + 6144] + pbuf[a + 7168]));
            po0 = edst[ebase + e] * 32 + (pass << 4) + oo;
            idx = tid + 512;
            e = idx >> 4; oo = idx & 15;
            xbE = ((e >> 2) ^ (e >> 5)) & 1;
            a = ((e ^ xbE) << 4) + oo;
            pv1 = ((pbuf[a]          + pbuf[a + 1024]) + (pbuf[a + 2048] + pbuf[a + 3072]))
                + ((pbuf[a + 4096]   + pbuf[a + 5120]) + (pbuf[a + 6144] + pbuf[a + 7168]));
            po1 = edst[ebase + e] * 32 + (pass << 4) + oo;
        }
    }
    // flush last tile's atomics
    atomicAdd(out + po0, pv0);
    atomicAdd(out + po1, pv1);
}

extern "C" void kernel_launch(void* const* d_in, const int* in_sizes, int n_in,
                              void* d_out, int out_size, void* d_ws, size_t ws_size,
                              hipStream_t stream) {
    const float* nf   = (const float*)d_in[0];
    const float* ef   = (const float*)d_in[1];
    const int*   src  = (const int*)  d_in[2];
    const int*   dst  = (const int*)  d_in[3];
    const float* W1   = (const float*)d_in[4];
    const float* b1   = (const float*)d_in[5];
    const float* W2   = (const float*)d_in[6];
    const float* b2   = (const float*)d_in[7];
    const float* bias = (const float*)d_in[8];
    float* out = (float*)d_out;
    short* W2p = (short*)d_ws;                 // 262144 B bf16 W2, packed per o-half (L2-resident)

    setup_kernel<<<OUT4_BLKS + W2C_BLKS, 256, 0, stream>>>(W2, bias, out, W2p);
    mpnn_kernel<<<NBLK, 512, LDS_BYTES, stream>>>(nf, ef, src, dst, W1, b1, b2, W2p, out);
}

// Round 12
// 186.592 us; speedup vs baseline: 1.4389x; 1.1190x over previous
//
#include <hip/hip_runtime.h>

// NNConv / MPNN layer, fully fused — v7: full-pass B prefetch (fixes v6's exposed L2 latency).
//   h  = relu(ef @ W1 + b1)            [E,128]   (bf16 MFMA, K=16)
//   We = h @ W2 + b2                   [E,32,32] (bf16 MFMA, K=128, acc in regs, never stored)
//   msg= einsum('ei,eio->eo', nf[src], We)       (fp32 VALU on acc tiles)
//   out= segment_sum(msg, dst) + bias            (fp32 global atomics, out pre-init to bias)
//
// v6 post-mortem: B-from-L2 with 2-deep rolling window regressed (147us vs v4's 100.5):
// ~64-100cyc lookahead vs ~200cyc L2 latency -> every ks stalls (MfmaUtil 22->15).
// Occupancy stayed ~21% at VGPR=88/LDS=62KB -> 2 blocks/CU never happens; stop betting on it.
// v7: keep v6's verified structure; load ALL 16 B-frags into registers BEFORE barrier D.
// VMEM pipelines them (~270cyc incl latency) under barrier D + phase0 + phase1 + barrier E
// (>=1Kcyc) -> K-loop runs B from registers: 0 B-side DS reads AND 0 load waits.
// bfr[16] = 64 VGPR, statically indexed (full unroll). __launch_bounds__(512) WITHOUT a
// min-waves clamp (v5's spill was the ,4 clamp, not the array). Est peak live ~170 <= 256.

#define E_TOTAL   200000
#define N_NODES   50000
#define TILES     3125          // E_TOTAL / 64
#define OUT4      400000        // N_NODES*32 / 4
#define OUT4_BLKS 1563          // ceil(OUT4/256)
#define W2C_BLKS  64            // 16384 16B-chunks / 256
#define NBLK      512
#define NTL_BIG   53            // TILES % NBLK: blocks 0..52 own 7 tiles, rest 6
#define LDS_BYTES 61952         // 4K W1Ts + 16K Hs + 8.5K XsT + 32K pbuf (no alias)

typedef short short8  __attribute__((ext_vector_type(8)));
typedef float f32x4   __attribute__((ext_vector_type(4)));
typedef float f32x16  __attribute__((ext_vector_type(16)));

__device__ __forceinline__ short f2bf(float f) {
    // round-to-nearest-even fp32 -> bf16 (inputs finite)
    union { float f; unsigned u; } cv; cv.f = f;
    unsigned r = cv.u + 0x7fffu + ((cv.u >> 16) & 1u);
    return (short)(r >> 16);
}

// ---------------- setup: out = bias (float4); W2 f32 -> bf16 packed image (dest-major) ----
// W2p short idx = p*65536 + ks*8192 + ct*512 + lhg*256 + cc*8 + j
//   where c = ct*32+cc (= i*16 + o15), k = ks*16 + lhg*8 + j, src = W2[k*1024 + i*32 + p*16 + o15]
__global__ __launch_bounds__(256) void setup_kernel(const float* __restrict__ W2,
                                                    const float* __restrict__ bias,
                                                    float* __restrict__ out,
                                                    short* __restrict__ W2p) {
    int bid = blockIdx.x, tid = threadIdx.x;
    if (bid < OUT4_BLKS) {
        int i4 = bid * 256 + tid;
        if (i4 < OUT4) {
            float4 bv = *(const float4*)(bias + ((i4 & 7) << 2));
            *(float4*)(out + (size_t)i4 * 4) = bv;
        }
    } else {
        int q = (bid - OUT4_BLKS) * 256 + tid;    // 0..16383: one 16B dest chunk
        int p  = q >> 13;
        int ch = q & 8191;
        int ks = ch >> 10, ct = (ch >> 6) & 15, lhg = (ch >> 5) & 1, cc = ch & 31;
        int c  = ct * 32 + cc;
        int i  = c >> 4, o15 = c & 15;
        int ci = i * 32 + p * 16 + o15;
        int kb = ks * 16 + lhg * 8;
        short8 pk;
        #pragma unroll
        for (int j = 0; j < 8; ++j) pk[j] = f2bf(W2[(size_t)(kb + j) * 1024 + ci]);
        *(short8*)(W2p + (size_t)q * 8) = pk;
    }
}

// ---------------- main fused kernel ----------------
__global__ __launch_bounds__(512) void mpnn_kernel(const float* __restrict__ nf,
                                                   const float* __restrict__ ef,
                                                   const int*   __restrict__ esrc,
                                                   const int*   __restrict__ edst,
                                                   const float* __restrict__ W1,
                                                   const float* __restrict__ b1,
                                                   const float* __restrict__ b2,
                                                   const short* __restrict__ W2p,
                                                   float* __restrict__ out) {
    extern __shared__ __align__(16) unsigned char smem[];
    short* W1Ts = (short*)(smem);              //   4096 B: [128 c][16 k] bf16 swizzled (prologue only)
    short* Hs   = (short*)(smem + 4096);       //  16384 B: [G 16][e^(G&7) 64] x 16B  (live D->C)
    float* XsT  = (float*)(smem + 20480);      //   8704 B: [32 i][68 e-pad] f32      (live phase0->C)
    float* pbuf = (float*)(smem + 29184);      //  32768 B: 8 slabs [64 e'][16 o] f32 (own region, no alias)

    const int tid = threadIdx.x;
    const int w   = tid >> 6;           // wave 0..7
    const int l31 = tid & 31;
    const int lh  = (tid >> 5) & 1;     // k-half within wave
    const int o15 = l31 & 15;
    const int ib  = l31 >> 4;           // i-lsb within packed col
    const int xbw = lh ^ ib;            // pbuf row-lsb XOR
    const int bid = blockIdx.x;
    const int ntl = (bid < NTL_BIG) ? 7 : 6;
    const int itn = 2 * ntl;
    const int bofs = (w << 10) + lh * 256 + l31 * 8;   // per-lane B-frag offset (t=0); +512 for t=1

    // ---------------- prologue: W1Ts; prefetch tile=bid ----------------
    float4 xreg; short8 efreg;
    float  b2v0, b2v1;
    {   // W1 [16][128] f32 -> W1Ts[c][k] bf16 swizzled (once per block)
        int g = tid * 4; int i = g >> 7; int c0 = g & 127;
        float4 v = *(const float4*)(W1 + g);
        float vv[4] = {v.x, v.y, v.z, v.w};
        #pragma unroll
        for (int u = 0; u < 4; ++u) {
            int c = c0 + u;
            W1Ts[c * 16 + (((i >> 3) ^ ((c >> 2) & 1)) << 3) + (i & 7)] = f2bf(vv[u]);
        }
    }
    {   // prefetch first tile: x gather (redundant esrc read per 8 threads) + ef frag
        int s = esrc[bid * 64 + (tid >> 3)];
        xreg = *(const float4*)(nf + (size_t)s * 32 + (tid & 7) * 4);
        int eL = l31 + ((w & 1) << 5);
        const float* ep = ef + (size_t)(bid * 64 + eL) * 16 + lh * 8;
        float4 a0 = *(const float4*)(ep);
        float4 a1 = *(const float4*)(ep + 4);
        efreg[0] = f2bf(a0.x); efreg[1] = f2bf(a0.y); efreg[2] = f2bf(a0.z); efreg[3] = f2bf(a0.w);
        efreg[4] = f2bf(a1.x); efreg[5] = f2bf(a1.y); efreg[6] = f2bf(a1.z); efreg[7] = f2bf(a1.w);
    }
    b2v0 = b2[(4 * w + ib) * 32 + o15];
    b2v1 = b2[(4 * w + 2 + ib) * 32 + o15];
    const int   cW1  = ((w >> 1) << 5) + l31;          // phase-1 hidden col
    const float b1v  = b1[cW1];

    __syncthreads();                                    // W1Ts visible
    const short8 w1frag = *(const short8*)(W1Ts + cW1 * 16 + ((lh ^ ((cW1 >> 2) & 1)) << 3));

    // deferred-atomic pending state (issued one iteration later, flushed after loop)
    float  pv0 = 0.f, pv1 = 0.f;
    int    po0 = 0,   po1 = 0;

    for (int it = 0; it < itn; ++it) {
        const int pass = (it >= ntl) ? 1 : 0;
        const int tile = bid + (it - pass * ntl) * NBLK;
        const int ebase = tile * 64;

        if (it == ntl) {   // switch to o-half 1: only the b2 constants change
            b2v0 = b2[(4 * w + ib) * 32 + 16 + o15];
            b2v1 = b2[(4 * w + 2 + ib) * 32 + 16 + o15];
        }

        // Issue ALL 16 B-frag loads for this pass now: they pipeline on VMEM and land
        // under barrier D + phase0 + phase1 + barrier E (>=1Kcyc >> ~270cyc needed).
        const short* Wb = W2p + (pass << 16) + bofs;
        short8 bfr[16];                       // 64 VGPR, all indices compile-time (full unroll)
        #pragma unroll
        for (int j = 0; j < 8; ++j) {
            bfr[2 * j]     = *(const short8*)(Wb + j * 8192);
            bfr[2 * j + 1] = *(const short8*)(Wb + j * 8192 + 512);
        }

        __syncthreads();   // D: prev iter's pbuf reads done -> Hs/XsT/pbuf writable

        // ---- phase 0: commit prefetched x -> XsT (transposed) ----
        {
            int e = tid >> 3, i4 = (tid & 7) * 4;
            XsT[(i4 + 0) * 68 + e] = xreg.x;
            XsT[(i4 + 1) * 68 + e] = xreg.y;
            XsT[(i4 + 2) * 68 + e] = xreg.z;
            XsT[(i4 + 3) * 68 + e] = xreg.w;
        }

        // ---- phase 1: h = relu(ef@W1+b1) -> Hs ----
        {
            f32x16 hacc;
            #pragma unroll
            for (int q = 0; q < 16; ++q) hacc[q] = 0.f;
            hacc = __builtin_amdgcn_mfma_f32_32x32x16_bf16(efreg, w1frag, hacc, 0, 0, 0);
            const int mh = w & 1, G1 = cW1 >> 3, j1 = cW1 & 7;
            #pragma unroll
            for (int r = 0; r < 16; ++r) {
                int ee = (r & 3) + ((r >> 2) << 3) + (lh << 2) + (mh << 5);
                float v = fmaxf(hacc[r] + b1v, 0.f);
                Hs[G1 * 512 + ((ee ^ (G1 & 7)) << 3) + j1] = f2bf(v);
            }
        }
        __syncthreads();   // E: Hs, XsT visible

        // next-tile index for prefetch (clamped on last iteration)
        int nit = it + 1; if (nit >= itn) nit = it;
        const int npass = (nit >= ntl) ? 1 : 0;
        const int nebase = (bid + (nit - npass * ntl) * NBLK) * 64;

        // ---- phase 2: K-loop; A-frags from LDS, B-frags already in registers ----
        f32x16 acc00, acc01, acc10, acc11;   // [t][mh]
        #pragma unroll
        for (int q = 0; q < 16; ++q) { acc00[q] = 0.f; acc01[q] = 0.f; acc10[q] = 0.f; acc11[q] = 0.f; }
        int pre_s = 0;
        #pragma unroll
        for (int ks = 0; ks < 8; ++ks) {
            const int G  = 2 * ks + lh;
            const int ax = ((l31 ^ (G & 7)) << 3);
            short8 afr0 = *(const short8*)(Hs + G * 512 + ax);          // e = l31
            short8 afr1 = *(const short8*)(Hs + G * 512 + ax + 256);    // e = l31+32
            acc00 = __builtin_amdgcn_mfma_f32_32x32x16_bf16(afr0, bfr[2 * ks    ], acc00, 0, 0, 0);
            acc01 = __builtin_amdgcn_mfma_f32_32x32x16_bf16(afr1, bfr[2 * ks    ], acc01, 0, 0, 0);
            acc10 = __builtin_amdgcn_mfma_f32_32x32x16_bf16(afr0, bfr[2 * ks + 1], acc10, 0, 0, 0);
            acc11 = __builtin_amdgcn_mfma_f32_32x32x16_bf16(afr1, bfr[2 * ks + 1], acc11, 0, 0, 0);
            if (ks == 1) pre_s = esrc[nebase + (tid >> 3)];
            if (ks == 3) {
                int eL = l31 + ((w & 1) << 5);
                const float* ep = ef + (size_t)(nebase + eL) * 16 + lh * 8;
                float4 a0 = *(const float4*)(ep);
                float4 a1 = *(const float4*)(ep + 4);
                efreg[0] = f2bf(a0.x); efreg[1] = f2bf(a0.y); efreg[2] = f2bf(a0.z); efreg[3] = f2bf(a0.w);
                efreg[4] = f2bf(a1.x); efreg[5] = f2bf(a1.y); efreg[6] = f2bf(a1.z); efreg[7] = f2bf(a1.w);
            }
            if (ks == 5) xreg = *(const float4*)(nf + (size_t)pre_s * 32 + (tid & 7) * 4);
            if (ks == 6 && it > 0) {   // prev tile's atomics: newest VMEM, drain by barrier D
                atomicAdd(out + po0, pv0);
                atomicAdd(out + po1, pv1);
            }
        }

        // ---- phase 3: contract with x (broadcast b128); shfl ib-pair; store pbuf directly ----
        const int xc0 = 4 * w + ib, xc1 = 4 * w + 2 + ib;
        float* pslab = pbuf + (w << 10);
        #pragma unroll
        for (int rq = 0; rq < 4; ++rq) {
            const int eb = 8 * rq + 4 * lh;                 // e-base for r = rq*4+u
            f32x4 A0 = *(const f32x4*)(XsT + xc0 * 68 + eb);
            f32x4 B0 = *(const f32x4*)(XsT + xc1 * 68 + eb);
            f32x4 A1 = *(const f32x4*)(XsT + xc0 * 68 + eb + 32);
            f32x4 B1 = *(const f32x4*)(XsT + xc1 * 68 + eb + 32);
            #pragma unroll
            for (int u = 0; u < 4; ++u) {
                int r = rq * 4 + u;
                float v = A0[u] * (acc00[r] + b2v0) + B0[u] * (acc10[r] + b2v1);
                v += __shfl_xor(v, 16);
                float v1 = A1[u] * (acc01[r] + b2v0) + B1[u] * (acc11[r] + b2v1);
                v1 += __shfl_xor(v1, 16);
                int e = u + 8 * rq + 4 * lh + (ib << 5);
                pslab[((e ^ xbw) << 4) + o15] = ib ? v1 : v;   // own slab, 2-way banked
            }
        }
        __syncthreads();   // C: all pbuf slabs written
        {   // final reduce over 8 slabs -> pending registers (atomics issued next iteration)
            int idx = tid;
            int e = idx >> 4, oo = idx & 15;
            int xbE = ((e >> 2) ^ (e >> 5)) & 1;
            int a = ((e ^ xbE) << 4) + oo;
            pv0 = ((pbuf[a]          + pbuf[a + 1024]) + (pbuf[a + 2048] + pbuf[a + 3072]))
                + ((pbuf[a + 4096]   + pbuf[a + 5120]) + (pbuf[a + 6144] + pbuf[a + 7168]));
            po0 = edst[ebase + e] * 32 + (pass << 4) + oo;
            idx = tid + 512;
            e = idx >> 4; oo = idx & 15;
            xbE = ((e >> 2) ^ (e >> 5)) & 1;
            a = ((e ^ xbE) << 4) + oo;
            pv1 = ((pbuf[a]          + pbuf[a + 1024]) + (pbuf[a + 2048] + pbuf[a + 3072]))
                + ((pbuf[a + 4096]   + pbuf[a + 5120]) + (pbuf[a + 6144] + pbuf[a + 7168]));
            po1 = edst[ebase + e] * 32 + (pass << 4) + oo;
        }
    }
    // flush last tile's atomics
    atomicAdd(out + po0, pv0);
    atomicAdd(out + po1, pv1);
}

extern "C" void kernel_launch(void* const* d_in, const int* in_sizes, int n_in,
                              void* d_out, int out_size, void* d_ws, size_t ws_size,
                              hipStream_t stream) {
    const float* nf   = (const float*)d_in[0];
    const float* ef   = (const float*)d_in[1];
    const int*   src  = (const int*)  d_in[2];
    const int*   dst  = (const int*)  d_in[3];
    const float* W1   = (const float*)d_in[4];
    const float* b1   = (const float*)d_in[5];
    const float* W2   = (const float*)d_in[6];
    const float* b2   = (const float*)d_in[7];
    const float* bias = (const float*)d_in[8];
    float* out = (float*)d_out;
    short* W2p = (short*)d_ws;                 // 262144 B bf16 W2, packed per o-half (L2-resident)

    setup_kernel<<<OUT4_BLKS + W2C_BLKS, 256, 0, stream>>>(W2, bias, out, W2p);
    mpnn_kernel<<<NBLK, 512, LDS_BYTES, stream>>>(nf, ef, src, dst, W1, b1, b2, W2p, out);
}